// Round 3
// baseline (102.182 us; speedup 1.0000x reference)
//
#include <hip/hip_runtime.h>
#include <math.h>

#define NATOMS   4096
#define NRBF     16
#define NHID     64
#define CUTOFF2  25.0f
// ETA = 0.5*(5.0-0.5)/16 = 0.140625 ; 1/(2*ETA^2)
#define INV_2ETA2 25.283950617283951f
#define PI_OVER_CUTOFF 0.62831853071795865f  // pi / 5
#define CAP      96     // per-wave neighbor capacity (empirically OK: r2 passed)
#define NBLOCKS  (NATOMS / 4)   // 1024 main-kernel blocks

// ---- cell list (box 40, cutoff 5 -> 8^3 cells, lambda = 8 atoms/cell) ----
#define NC1      8
#define NCELLS   512
#define CELLCAP  32      // empirically sufficient (r2 passed, absmax 0)
#define INV_CELL 0.2f    // 1 / 5.0

// ws layout (float units):
//   [0, 1024)                     per-block partial energies
//   [4096, 4609)                  cnt[513] ints (cell 512 = dummy, always 0)
//   [5119]                        done counter (int)
//   [5120, 5120 + 512*32*4)       cells: float4[NCELLS][CELLCAP]
#define WS_PART_OFF   0
#define WS_CNT_OFF    4096
#define WS_DONE_OFF   5119
#define WS_CELLS_OFF  5120
#define WS_NEED_BYTES ((size_t)(WS_CELLS_OFF + NCELLS * CELLCAP * 4) * 4)

// ============================ cell-list path ============================

// Single block, 1024 threads: zero counters in LDS, bin all 4096 atoms via
// LDS atomics, flush cnt/cells to global, zero the done counter. Replaces
// memset + 16-block bin (2 dispatches -> 1).
__global__ __launch_bounds__(1024) void bin1_kernel(
    const float* __restrict__ pos,
    int* __restrict__ cnt,           // 513 ints
    int* __restrict__ done,          // 1 int
    float4* __restrict__ cells)
{
    __shared__ int lcnt[NCELLS + 1];
    const int tid = threadIdx.x;
    if (tid < NCELLS + 1) lcnt[tid] = 0;
    __syncthreads();

    // thread t owns atoms 4t..4t+3 : 3 coalesced float4 loads, register unpack
    const float4* src = (const float4*)pos;
    const float4 v0 = src[3 * tid + 0];  // x0 y0 z0 x1
    const float4 v1 = src[3 * tid + 1];  // y1 z1 x2 y2
    const float4 v2 = src[3 * tid + 2];  // z2 x3 y3 z3
    const float xs[4] = {v0.x, v0.w, v1.z, v2.y};
    const float ys[4] = {v0.y, v1.x, v1.w, v2.z};
    const float zs[4] = {v0.z, v1.y, v2.x, v2.w};
#pragma unroll
    for (int u = 0; u < 4; ++u) {
        const int cx = min((int)(xs[u] * INV_CELL), NC1 - 1);
        const int cy = min((int)(ys[u] * INV_CELL), NC1 - 1);
        const int cz = min((int)(zs[u] * INV_CELL), NC1 - 1);
        const int c  = (cz * NC1 + cy) * NC1 + cx;
        const int slot = atomicAdd(&lcnt[c], 1);          // LDS atomic
        if (slot < CELLCAP)
            cells[c * CELLCAP + slot] = make_float4(xs[u], ys[u], zs[u], 0.0f);
    }
    __syncthreads();
    if (tid < NCELLS + 1) cnt[tid] = lcnt[tid];
    if (tid == 0) *done = 0;
}

// One wave per atom; sieve = 27 neighbor cells (2 cells/iter, 32 lanes each).
// No barriers in the sieve/MLP (waves independent). Epilogue: block partial ->
// agent-scope release store; last block (acq-rel counter) sums 1024 partials
// with agent-scope loads and writes out[0]. 2 dispatches total for the path.
__global__ __launch_bounds__(256) void short_range_cells_kernel(
    const float* __restrict__ pos,
    const float* __restrict__ centers,
    const int* __restrict__ cnt,
    int* __restrict__ done,
    const float4* __restrict__ cells,
    const float* __restrict__ W1, const float* __restrict__ b1,
    const float* __restrict__ W2, const float* __restrict__ b2,
    const float* __restrict__ W3, const float* __restrict__ b3,
    float* __restrict__ ws,          // 1024 per-block partials
    float* __restrict__ out)
{
    __shared__ float sdist[4][CAP];     // 1.5 KB
    __shared__ float s_h1[4][NHID];     // 1 KB
    __shared__ float s_part[4];
    __shared__ int   s_last;

    const int tid  = threadIdx.x;
    const int lane = tid & 63;
    const int wave = tid >> 6;
    const int i    = blockIdx.x * 4 + wave;   // this wave's atom

    const float xi = pos[3 * i + 0];
    const float yi = pos[3 * i + 1];
    const float zi = pos[3 * i + 2];
    const int cxi = min((int)(xi * INV_CELL), NC1 - 1);
    const int cyi = min((int)(yi * INV_CELL), NC1 - 1);
    const int czi = min((int)(zi * INV_CELL), NC1 - 1);

    // lane l < 27 owns neighbor cell l (3x3x3); others own dummy cell 512
    // whose cnt is always 0.
    int nc = NCELLS;
    if (lane < 27) {
        const int cx = cxi + (lane % 3) - 1;
        const int cy = cyi + ((lane / 3) % 3) - 1;
        const int cz = czi + (lane / 9) - 1;
        if ((unsigned)cx < (unsigned)NC1 && (unsigned)cy < (unsigned)NC1 &&
            (unsigned)cz < (unsigned)NC1)
            nc = (cz * NC1 + cy) * NC1 + cx;
    }
    const int mycnt = min(cnt[nc], CELLCAP);

    // ---- sieve: 14 iterations x 2 cells; ballot + prefix compaction ----
    const int half = lane >> 5;   // which cell of the pair
    const int idx  = lane & 31;   // slot within that cell
    int base = 0;
#pragma unroll
    for (int t = 0; t < 14; ++t) {
        const int cl = 2 * t + half;               // 0..27 (27 -> dummy lane)
        const int c  = __shfl(nc,    cl, 64);
        const int cn = __shfl(mycnt, cl, 64);
        float sq = 1e30f;
        bool pass = false;
        if (idx < cn) {
            const float4 p = cells[c * CELLCAP + idx];
            const float dx = p.x - xi;
            const float dy = p.y - yi;
            const float dz = p.z - zi;
            sq = dx * dx + dy * dy + dz * dz;
            pass = (sq > 0.0f) && (sq < CUTOFF2);
        }
        const unsigned long long m = __ballot(pass);
        if (pass) {
            const int slot = base + (int)__popcll(m & ((1ull << lane) - 1ull));
            if (slot < CAP) sdist[wave][slot] = sqrtf(sq);
        }
        base += (int)__popcll(m);
    }
    const int count = min(base, CAP);

    // ---- dense RBF, transposed: entry = e0 + (lane>>4), feature = lane&15 ----
    const int   kf   = lane & 15;
    const int   eoff = lane >> 4;
    const float ck   = centers[kf];
    float acc = 0.0f;
    for (int e0 = 0; e0 < count; e0 += 4) {
        const int e = e0 + eoff;
        if (e < count) {
            const float d = sdist[wave][e];
            const float w = 0.5f * (1.0f + __cosf(d * PI_OVER_CUTOFF));
            const float t = d - ck;
            acc += w * __expf(-(t * t) * INV_2ETA2);
        }
    }
    acc += __shfl_xor(acc, 16, 64);
    acc += __shfl_xor(acc, 32, 64);

    // ---- per-wave MLP: lane n owns hidden unit n (NHID == 64) ----
    float h = b1[lane];
#pragma unroll
    for (int k = 0; k < NRBF; ++k)
        h += __shfl(acc, k, 64) * W1[k * NHID + lane];   // broadcast feat[k]
    h = h / (1.0f + __expf(-h));         // silu
    s_h1[wave][lane] = h;
    // single-wave producer/consumer on own LDS row: program order suffices
    float h2 = b2[lane];
#pragma unroll 8
    for (int m = 0; m < NHID; ++m) h2 += s_h1[wave][m] * W2[m * NHID + lane];
    h2 = h2 / (1.0f + __expf(-h2));      // silu
    float e = h2 * W3[lane];
#pragma unroll
    for (int off = 32; off > 0; off >>= 1) e += __shfl_xor(e, off, 64);
    if (lane == 0) s_part[wave] = e;
    __syncthreads();

    // ---- block partial -> ws[bid]; last block reduces (rocPRIM idiom) ----
    if (tid == 0) {
        const float p = s_part[0] + s_part[1] + s_part[2] + s_part[3];
        __hip_atomic_store(&ws[blockIdx.x], p, __ATOMIC_RELEASE,
                           __HIP_MEMORY_SCOPE_AGENT);
        const int old = __hip_atomic_fetch_add(done, 1, __ATOMIC_ACQ_REL,
                                               __HIP_MEMORY_SCOPE_AGENT);
        s_last = (old == NBLOCKS - 1);
    }
    __syncthreads();
    if (s_last) {
        float s = 0.0f;
#pragma unroll
        for (int k = 0; k < NBLOCKS / 256; ++k)   // 4 coalesced rounds
            s += __hip_atomic_load(&ws[tid + 256 * k], __ATOMIC_RELAXED,
                                   __HIP_MEMORY_SCOPE_AGENT);
#pragma unroll
        for (int off = 32; off > 0; off >>= 1) s += __shfl_xor(s, off, 64);
        if (lane == 0) s_part[wave] = s;
        __syncthreads();
        if (tid == 0)
            out[0] = s_part[0] + s_part[1] + s_part[2] + s_part[3]
                   + (float)NATOMS * b3[0];
    }
}

// ==================== fallback: previous verified path ====================
// (verbatim 83 us kernel; used only if ws_size < WS_NEED_BYTES)

#define CHUNK 1024

__global__ __launch_bounds__(256) void short_range_fb_kernel(
    const float* __restrict__ pos,
    const float* __restrict__ centers,
    const float* __restrict__ W1, const float* __restrict__ b1,
    const float* __restrict__ W2, const float* __restrict__ b2,
    const float* __restrict__ W3,
    float* __restrict__ ws)
{
    __shared__ float spos[3 * CHUNK];
    __shared__ float sdist[4][CAP];
    __shared__ float s_h1[4][NHID];
    __shared__ float s_part[4];

    const int tid  = threadIdx.x;
    const int lane = tid & 63;
    const int wave = tid >> 6;
    const int i    = blockIdx.x * 4 + wave;

    float* sx = spos;
    float* sy = spos + CHUNK;
    float* sz = spos + 2 * CHUNK;

    const float xi = pos[3 * i + 0];
    const float yi = pos[3 * i + 1];
    const float zi = pos[3 * i + 2];

    int base = 0;
    for (int c = 0; c < 4; ++c) {
        {
            const float4* src = (const float4*)(pos + c * (3 * CHUNK));
            const float4 v0 = src[3 * tid + 0];
            const float4 v1 = src[3 * tid + 1];
            const float4 v2 = src[3 * tid + 2];
            *(float4*)&sx[4 * tid] = make_float4(v0.x, v0.w, v1.z, v2.y);
            *(float4*)&sy[4 * tid] = make_float4(v0.y, v1.x, v1.w, v2.z);
            *(float4*)&sz[4 * tid] = make_float4(v0.z, v1.y, v2.x, v2.w);
        }
        __syncthreads();
#pragma unroll
        for (int it = 0; it < 4; ++it) {
            const int a = it * 256 + lane * 4;
            const float4 vx = *(const float4*)&sx[a];
            const float4 vy = *(const float4*)&sy[a];
            const float4 vz = *(const float4*)&sz[a];
#pragma unroll
            for (int u = 0; u < 4; ++u) {
                const float dx = ((const float*)&vx)[u] - xi;
                const float dy = ((const float*)&vy)[u] - yi;
                const float dz = ((const float*)&vz)[u] - zi;
                const float sq = dx * dx + dy * dy + dz * dz;
                const bool pass = (sq > 0.0f) && (sq < CUTOFF2);
                const unsigned long long mask = __ballot(pass);
                if (pass) {
                    const int slot = base + (int)__popcll(mask & ((1ull << lane) - 1ull));
                    if (slot < CAP) sdist[wave][slot] = sqrtf(sq);
                }
                base += (int)__popcll(mask);
            }
        }
        __syncthreads();
    }
    const int count = min(base, CAP);

    const int   kf   = lane & 15;
    const int   eoff = lane >> 4;
    const float ck   = centers[kf];
    float acc = 0.0f;
    for (int e0 = 0; e0 < count; e0 += 4) {
        const int e = e0 + eoff;
        if (e < count) {
            const float d = sdist[wave][e];
            const float w = 0.5f * (1.0f + __cosf(d * PI_OVER_CUTOFF));
            const float t = d - ck;
            acc += w * __expf(-(t * t) * INV_2ETA2);
        }
    }
    acc += __shfl_xor(acc, 16, 64);
    acc += __shfl_xor(acc, 32, 64);

    float h = b1[lane];
#pragma unroll
    for (int k = 0; k < NRBF; ++k)
        h += __shfl(acc, k, 64) * W1[k * NHID + lane];
    h = h / (1.0f + __expf(-h));
    s_h1[wave][lane] = h;
    float h2 = b2[lane];
#pragma unroll 8
    for (int m = 0; m < NHID; ++m) h2 += s_h1[wave][m] * W2[m * NHID + lane];
    h2 = h2 / (1.0f + __expf(-h2));
    float e = h2 * W3[lane];
#pragma unroll
    for (int off = 32; off > 0; off >>= 1) e += __shfl_xor(e, off, 64);
    if (lane == 0) s_part[wave] = e;
    __syncthreads();
    if (tid == 0)
        ws[blockIdx.x] = s_part[0] + s_part[1] + s_part[2] + s_part[3];
}

__global__ __launch_bounds__(256) void reduce_fb_kernel(
    const float* __restrict__ ws, const float* __restrict__ b3,
    float* __restrict__ out)
{
    __shared__ float s_part[4];
    const int tid  = threadIdx.x;
    const int lane = tid & 63;
    const int wave = tid >> 6;

    const float4 v = ((const float4*)ws)[tid];
    float s = v.x + v.y + v.z + v.w;
#pragma unroll
    for (int off = 32; off > 0; off >>= 1) s += __shfl_xor(s, off, 64);
    if (lane == 0) s_part[wave] = s;
    __syncthreads();
    if (tid == 0)
        out[0] = s_part[0] + s_part[1] + s_part[2] + s_part[3]
               + (float)NATOMS * b3[0];
}

// ============================== launch ==============================

extern "C" void kernel_launch(void* const* d_in, const int* in_sizes, int n_in,
                              void* d_out, int out_size, void* d_ws, size_t ws_size,
                              hipStream_t stream) {
    const float* pos     = (const float*)d_in[0];
    const float* centers = (const float*)d_in[1];
    const float* W1      = (const float*)d_in[2];
    const float* b1      = (const float*)d_in[3];
    const float* W2      = (const float*)d_in[4];
    const float* b2      = (const float*)d_in[5];
    const float* W3      = (const float*)d_in[6];
    const float* b3      = (const float*)d_in[7];
    float* out = (float*)d_out;
    float* ws  = (float*)d_ws;

    if (ws_size >= WS_NEED_BYTES) {
        int*    cnt   = (int*)(ws + WS_CNT_OFF);
        int*    done  = (int*)(ws + WS_DONE_OFF);
        float4* cells = (float4*)(ws + WS_CELLS_OFF);
        hipLaunchKernelGGL(bin1_kernel, dim3(1), dim3(1024), 0, stream,
                           pos, cnt, done, cells);
        hipLaunchKernelGGL(short_range_cells_kernel, dim3(NBLOCKS), dim3(256), 0, stream,
                           pos, centers, cnt, done, cells,
                           W1, b1, W2, b2, W3, b3,
                           ws + WS_PART_OFF, out);
    } else {
        // workspace too small for cell lists: previous verified path
        hipLaunchKernelGGL(short_range_fb_kernel, dim3(NATOMS / 4), dim3(256), 0, stream,
                           pos, centers, W1, b1, W2, b2, W3, ws);
        hipLaunchKernelGGL(reduce_fb_kernel, dim3(1), dim3(256), 0, stream,
                           ws, b3, out);
    }
}